// Round 2
// baseline (187.368 us; speedup 1.0000x reference)
//
#include <hip/hip_runtime.h>
#include <cstdint>
#include <cstddef>

// ---------------------------------------------------------------------------
// HierarchicalSparseAttention  B=2 L=4096 D=1024 H=16 DH=64
// Pipeline: cvt(f32->bf16) -> QKV GEMM (bf16 MFMA) -> tree build -> sparse attn
//           -> output GEMM (+bias, f32)
// ---------------------------------------------------------------------------

typedef __bf16 bf16;
typedef __bf16 bf16x8 __attribute__((ext_vector_type(8)));
typedef __bf16 bf16x4 __attribute__((ext_vector_type(4)));
typedef float  f32x4  __attribute__((ext_vector_type(4)));

#define L_SEQ  4096
#define NFLAT  8192   /* padded 2L-1 = 8191 */

// flat offset of level l:  OFF(l) = 8192 - (8192>>l)   (exact for l=0..12)
__device__ __forceinline__ int off_l(int l) { return 8192 - (8192 >> l); }

// ---- async global->LDS, 16B per lane; lds base must be wave-uniform --------
__device__ __forceinline__ void glds16(const bf16* g, bf16* l) {
  __builtin_amdgcn_global_load_lds(
      (const __attribute__((address_space(1))) unsigned int*)g,
      (__attribute__((address_space(3))) unsigned int*)l, 16, 0, 0);
}

// ---------------------------------------------------------------------------
// fp32 -> bf16 conversion (vectorized float4 -> bf16x4)
// ---------------------------------------------------------------------------
__global__ __launch_bounds__(256) void cvt_kernel(const float* __restrict__ src,
                                                  bf16* __restrict__ dst, int n4) {
  int i = blockIdx.x * 256 + threadIdx.x;
  if (i < n4) {
    const float4 v = ((const float4*)src)[i];
    bf16x4 o;
    o[0] = (bf16)v.x; o[1] = (bf16)v.y; o[2] = (bf16)v.z; o[3] = (bf16)v.w;
    *(bf16x4*)(dst + (size_t)i * 4) = o;
  }
}

// ---------------------------------------------------------------------------
// GEMM core: C(128x128) = A(128xK) * W(128xK)^T, K=1024, bf16, m97 structure.
// A row-major [M][1024], W row-major [N][1024] (i.e. B^T input).
// 256 threads = 4 waves (2x2), each wave 64x64 via 4x4 frags of 16x16x32.
// ---------------------------------------------------------------------------
__device__ __forceinline__ void gemm_core(const bf16* __restrict__ A,
                                          const bf16* __restrict__ W,
                                          int tm, int tn, bf16* As, bf16* Bs,
                                          f32x4 (&acc)[4][4]) {
  const int tid  = threadIdx.x;
  const int wave = tid >> 6, lane = tid & 63;
  const int wm = (wave >> 1) * 64, wn = (wave & 1) * 64;
  for (int k0 = 0; k0 < 1024; k0 += 32) {
#pragma unroll
    for (int c = 0; c < 2; c++) {
      const int base = c * 4096 + wave * 1024;  // wave-uniform byte offset in 8KB tile
      const int off  = base + lane * 16;        // per-lane byte offset
      const int row  = off >> 6;                // 64B per 32-elem row
      const int kk   = (off & 63) >> 1;         // bf16 col within row
      glds16(A + (size_t)(tm * 128 + row) * 1024 + k0 + kk, As + (base >> 1));
      glds16(W + (size_t)(tn * 128 + row) * 1024 + k0 + kk, Bs + (base >> 1));
    }
    __syncthreads();
    bf16x8 af[4], bfr[4];
#pragma unroll
    for (int i = 0; i < 4; i++) {
      af[i]  = *(const bf16x8*)&As[(wm + i * 16 + (lane & 15)) * 32 + (lane >> 4) * 8];
      bfr[i] = *(const bf16x8*)&Bs[(wn + i * 16 + (lane & 15)) * 32 + (lane >> 4) * 8];
    }
#pragma unroll
    for (int i = 0; i < 4; i++)
#pragma unroll
      for (int j = 0; j < 4; j++)
        acc[i][j] = __builtin_amdgcn_mfma_f32_16x16x32_bf16(af[i], bfr[j], acc[i][j], 0, 0, 0);
    __syncthreads();
  }
}

// QKV projections. grid = (512, 3): x -> tile (tm = x&63, tn = x>>6), y -> {Q,K,V}
// Writes transposed layouts: Q -> [bh][l][64], K/V -> flat[bh][node][64] level-0.
__global__ __launch_bounds__(256) void gemm_qkv_kernel(
    const bf16* __restrict__ qx, const bf16* __restrict__ kx, const bf16* __restrict__ vx,
    const bf16* __restrict__ wq, const bf16* __restrict__ wk, const bf16* __restrict__ wv,
    bf16* __restrict__ Qb, bf16* __restrict__ fK, bf16* __restrict__ fV) {
  __shared__ __align__(16) bf16 As[128 * 32];
  __shared__ __align__(16) bf16 Bs[128 * 32];
  const int z = blockIdx.y;
  const bf16* A = (z == 0) ? qx : (z == 1) ? kx : vx;
  const bf16* W = (z == 0) ? wq : (z == 1) ? wk : wv;
  bf16* D       = (z == 0) ? Qb : (z == 1) ? fK : fV;
  const int lstr = (z == 0) ? L_SEQ : NFLAT;
  const int tm = blockIdx.x & 63, tn = blockIdx.x >> 6;
  f32x4 acc[4][4] = {};
  gemm_core(A, W, tm, tn, As, Bs, acc);
  const int lane = threadIdx.x & 63, wave = threadIdx.x >> 6;
  const int m0 = tm * 128 + (wave >> 1) * 64 + (lane >> 4) * 4;
  const int n0 = tn * 128 + (wave & 1) * 64 + (lane & 15);
#pragma unroll
  for (int i = 0; i < 4; i++)
#pragma unroll
    for (int j = 0; j < 4; j++)
#pragma unroll
      for (int r = 0; r < 4; r++) {
        const int m = m0 + i * 16 + r;
        const int n = n0 + j * 16;
        const int b = m >> 12, l = m & 4095;
        const int h = n >> 6,  dh = n & 63;
        D[((size_t)(b * 16 + h) * lstr + l) * 64 + dh] = (bf16)acc[i][j][r];
      }
}

// Output projection + bias, f32 output row-major (8192 x 1024). grid = 512.
__global__ __launch_bounds__(256) void gemm_out_kernel(
    const bf16* __restrict__ Ob, const bf16* __restrict__ wo,
    const float* __restrict__ bo, float* __restrict__ out) {
  __shared__ __align__(16) bf16 As[128 * 32];
  __shared__ __align__(16) bf16 Bs[128 * 32];
  const int tm = blockIdx.x & 63, tn = blockIdx.x >> 6;
  f32x4 acc[4][4] = {};
  gemm_core(Ob, wo, tm, tn, As, Bs, acc);
  const int lane = threadIdx.x & 63, wave = threadIdx.x >> 6;
  const int m0 = tm * 128 + (wave >> 1) * 64 + (lane >> 4) * 4;
  const int n0 = tn * 128 + (wave & 1) * 64 + (lane & 15);
#pragma unroll
  for (int i = 0; i < 4; i++)
#pragma unroll
    for (int j = 0; j < 4; j++)
#pragma unroll
      for (int r = 0; r < 4; r++) {
        const int m = m0 + i * 16 + r;
        const int n = n0 + j * 16;
        out[(size_t)m * 1024 + n] = acc[i][j][r] + bo[n];
      }
}

// ---------------------------------------------------------------------------
// Tree build, levels 1..6: one wave per (bh, group of 64 leaves).
// Binary-counter pairwise accumulation; K stores mean (sum * 2^-l), V sum.
// ---------------------------------------------------------------------------
__global__ __launch_bounds__(256) void tree_low(bf16* __restrict__ fK, bf16* __restrict__ fV) {
  const int gw   = (blockIdx.x * 256 + threadIdx.x) >> 6;  // 0..2047
  const int lane = threadIdx.x & 63;
  const int bh = gw >> 6, j6 = gw & 63;
  const size_t base = (size_t)bh * NFLAT * 64 + lane;
  float pk[7], pv[7];
#pragma unroll
  for (int i = 0; i < 64; i++) {
    const int leaf = j6 * 64 + i;
    float ck = (float)fK[base + (size_t)leaf * 64];
    float cv = (float)fV[base + (size_t)leaf * 64];
#pragma unroll
    for (int l = 1; l <= 6; l++) {
      if (((i + 1) & ((1 << l) - 1)) != 0) { pk[l] = ck; pv[l] = cv; break; }
      ck += pk[l]; cv += pv[l];
      const int j = leaf >> l;
      fK[base + (size_t)(off_l(l) + j) * 64] = (bf16)(ck * (1.0f / (1 << l)));
      fV[base + (size_t)(off_l(l) + j) * 64] = (bf16)cv;
    }
  }
}

// Tree build, levels 7..12 from level 6 (64 nodes per bh). grid 32 x 64 thr.
__global__ __launch_bounds__(64) void tree_high(bf16* __restrict__ fK, bf16* __restrict__ fV) {
  const int bh = blockIdx.x;
  const int lane = threadIdx.x;
  const size_t base = (size_t)bh * NFLAT * 64 + lane;
  float pk[7], pv[7];
#pragma unroll
  for (int i = 0; i < 64; i++) {
    float ck = (float)fK[base + (size_t)(off_l(6) + i) * 64];
    float cv = (float)fV[base + (size_t)(off_l(6) + i) * 64];
#pragma unroll
    for (int s = 1; s <= 6; s++) {
      if (((i + 1) & ((1 << s) - 1)) != 0) { pk[s] = ck; pv[s] = cv; break; }
      ck += pk[s]; cv += pv[s];
      const int j = i >> s;
      fK[base + (size_t)(off_l(6 + s) + j) * 64] = (bf16)(ck * (1.0f / (1 << s)));
      fV[base + (size_t)(off_l(6 + s) + j) * 64] = (bf16)cv;
    }
  }
}

// ---------------------------------------------------------------------------
// Sparse attention: per token 13 candidates (self + levels 0..11).
//   neighbor flat idx at level l = OFF(l) + ((n>>l)^1); valid iff (n>>l)&1.
// Block = 1 wave = 64 consecutive tokens of one (b,h). Stage the 132 distinct
// K/V rows in LDS (XOR-swizzled: chunk' = chunk ^ (row&7) to break the
// 32-way bank conflict of 128B rows).
// grid = (64 chunks, 32 bh)
// ---------------------------------------------------------------------------
__global__ __launch_bounds__(64) void attn_kernel(
    const bf16* __restrict__ Qb, const bf16* __restrict__ fK,
    const bf16* __restrict__ fV, bf16* __restrict__ Ob) {
  __shared__ __align__(16) unsigned short Kl[132 * 64];
  __shared__ __align__(16) unsigned short Vl[132 * 64];
  const int t0  = blockIdx.x * 64;
  const int bh  = blockIdx.y;
  const int tid = threadIdx.x;
  const size_t fb = (size_t)bh * NFLAT * 64;

  // --- stage 132 rows x 128B of K and V ---
  for (int u = tid; u < 132 * 8; u += 64) {
    const int r = u >> 3, c = u & 7;
    int flat;
    if      (r < 64)  flat = t0 + r;                          // level 0 (chunk itself)
    else if (r < 96)  flat = 4096 + (t0 >> 1) + (r - 64);     // level 1
    else if (r < 112) flat = 6144 + (t0 >> 2) + (r - 96);     // level 2
    else if (r < 120) flat = 7168 + (t0 >> 3) + (r - 112);    // level 3
    else if (r < 124) flat = 7680 + (t0 >> 4) + (r - 120);    // level 4
    else if (r < 126) flat = 7936 + (t0 >> 5) + (r - 124);    // level 5
    else { const int l = r - 120; flat = (8192 - (8192 >> l) + (t0 >> l)) ^ 1; } // lvl 6..11
    const int cc = c ^ (r & 7);
    const uint4 kk = *(const uint4*)((const char*)(fK + fb + (size_t)flat * 64) + c * 16);
    const uint4 vv = *(const uint4*)((const char*)(fV + fb + (size_t)flat * 64) + c * 16);
    *(uint4*)((char*)Kl + r * 128 + cc * 16) = kk;
    *(uint4*)((char*)Vl + r * 128 + cc * 16) = vv;
  }
  __syncthreads();

  const int n = t0 + tid;
  int rows[13];
  rows[0] = tid;                                 // self
#pragma unroll
  for (int l = 0; l < 12; l++) {
    int r;
    if (l == 0)      r = tid ^ 1;
    else if (l <= 5) r = (128 - (128 >> l)) + (((n >> l) ^ 1) - (t0 >> l));
    else             r = 126 + (l - 6);
    rows[l + 1] = r;
  }

  // Q row -> 64 f32 regs
  float q[64];
  const bf16* Qr = Qb + ((size_t)bh * L_SEQ + n) * 64;
#pragma unroll
  for (int c = 0; c < 8; c++) {
    bf16x8 v = *(const bf16x8*)(Qr + c * 8);
#pragma unroll
    for (int j = 0; j < 8; j++) q[c * 8 + j] = (float)v[j];
  }

  // 13 logits
  float lg[13];
#pragma unroll
  for (int v = 0; v < 13; v++) {
    const int r = rows[v];
    float a = 0.f;
#pragma unroll
    for (int c = 0; c < 8; c++) {
      const int cc = c ^ (r & 7);
      const bf16x8 kv = *(const bf16x8*)((const char*)Kl + r * 128 + cc * 16);
#pragma unroll
      for (int j = 0; j < 8; j++) a += q[c * 8 + j] * (float)kv[j];
    }
    lg[v] = a * 0.125f;
  }
  // causal mask: level l masked iff (n>>l) even
#pragma unroll
  for (int v = 1; v < 13; v++)
    if (!((n >> (v - 1)) & 1)) lg[v] = -1e30f;

  // softmax over 13
  float mx = lg[0];
#pragma unroll
  for (int v = 1; v < 13; v++) mx = fmaxf(mx, lg[v]);
  float w[13], s = 0.f;
#pragma unroll
  for (int v = 0; v < 13; v++) { w[v] = __expf(lg[v] - mx); s += w[v]; }
  const float inv = 1.0f / s;

  // weighted V sum
  float o[64];
#pragma unroll
  for (int d = 0; d < 64; d++) o[d] = 0.f;
#pragma unroll
  for (int v = 0; v < 13; v++) {
    const int r = rows[v];
    const float wv = w[v];
#pragma unroll
    for (int c = 0; c < 8; c++) {
      const int cc = c ^ (r & 7);
      const bf16x8 vv = *(const bf16x8*)((const char*)Vl + r * 128 + cc * 16);
#pragma unroll
      for (int j = 0; j < 8; j++) o[c * 8 + j] += wv * (float)vv[j];
    }
  }

  // write O row-major (B*L, 1024): [(b*4096+n)*1024 + h*64 + d]
  bf16* Or = Ob + ((size_t)(bh >> 4) * L_SEQ + n) * 1024 + (size_t)(bh & 15) * 64;
#pragma unroll
  for (int c = 0; c < 8; c++) {
    bf16x8 ov;
#pragma unroll
    for (int j = 0; j < 8; j++) ov[j] = (bf16)(o[c * 8 + j] * inv);
    *(bf16x8*)(Or + c * 8) = ov;
  }
}

// ---------------------------------------------------------------------------
extern "C" void kernel_launch(void* const* d_in, const int* in_sizes, int n_in,
                              void* d_out, int out_size, void* d_ws, size_t ws_size,
                              hipStream_t stream) {
  const float* query = (const float*)d_in[0];
  const float* key   = (const float*)d_in[1];
  const float* value = (const float*)d_in[2];
  const float* Wq    = (const float*)d_in[3];
  const float* Wk    = (const float*)d_in[4];
  const float* Wv    = (const float*)d_in[5];
  const float* Wo    = (const float*)d_in[6];
  const float* bo    = (const float*)d_in[7];
  float* out = (float*)d_out;

  char* ws = (char*)d_ws;
  size_t off = 0;
  auto take = [&](size_t bytes) -> void* {
    void* p = ws + off;
    off += (bytes + 255) & ~(size_t)255;
    return p;
  };
  const size_t XB = (size_t)8192 * 1024 * 2;   // 16.78 MB
  const size_t WB = (size_t)1024 * 1024 * 2;   //  2.10 MB
  bf16* qx  = (bf16*)take(XB);
  bf16* kx  = (bf16*)take(XB);
  bf16* vx  = (bf16*)take(XB);
  bf16* wqx = (bf16*)take(WB);
  bf16* wkx = (bf16*)take(WB);
  bf16* wvx = (bf16*)take(WB);
  bf16* wox = (bf16*)take(WB);
  bf16* Qb  = (bf16*)take((size_t)32 * L_SEQ * 64 * 2);   // 16.78 MB
  bf16* fK  = (bf16*)take((size_t)32 * NFLAT * 64 * 2);   // 33.55 MB
  bf16* fV  = (bf16*)take((size_t)32 * NFLAT * 64 * 2);   // 33.55 MB
  bf16* Ob  = qx;  // alias: qx's last read is gemm_qkv; Ob first written by attn
  (void)in_sizes; (void)n_in; (void)out_size; (void)ws_size;

  // 1. fp32 -> bf16
  cvt_kernel<<<8192, 256, 0, stream>>>(query, qx, 2097152);
  cvt_kernel<<<8192, 256, 0, stream>>>(key,   kx, 2097152);
  cvt_kernel<<<8192, 256, 0, stream>>>(value, vx, 2097152);
  cvt_kernel<<<1024, 256, 0, stream>>>(Wq, wqx, 262144);
  cvt_kernel<<<1024, 256, 0, stream>>>(Wk, wkx, 262144);
  cvt_kernel<<<1024, 256, 0, stream>>>(Wv, wvx, 262144);
  cvt_kernel<<<1024, 256, 0, stream>>>(Wo, wox, 262144);

  // 2. Q/K/V projections
  gemm_qkv_kernel<<<dim3(512, 3), 256, 0, stream>>>(qx, kx, vx, wqx, wkx, wvx, Qb, fK, fV);

  // 3. hierarchy
  tree_low<<<512, 256, 0, stream>>>(fK, fV);
  tree_high<<<32, 64, 0, stream>>>(fK, fV);

  // 4. sparse attention
  attn_kernel<<<dim3(64, 32), 64, 0, stream>>>(Qb, fK, fV, Ob);

  // 5. output projection
  gemm_out_kernel<<<512, 256, 0, stream>>>(Ob, wox, bo, out);
}

// Round 3
// 179.125 us; speedup vs baseline: 1.0460x; 1.0460x over previous
//
#include <hip/hip_runtime.h>
#include <cstdint>
#include <cstddef>

// ---------------------------------------------------------------------------
// HierarchicalSparseAttention  B=2 L=4096 D=1024 H=16 DH=64
// cvt(f32->bf16) -> QKV GEMM (bf16 MFMA) -> tree build (LDS) -> sparse attn
// -> output GEMM (+bias, f32)
// ---------------------------------------------------------------------------

typedef __bf16 bf16;
typedef __bf16 bf16x8 __attribute__((ext_vector_type(8)));
typedef __bf16 bf16x4 __attribute__((ext_vector_type(4)));
typedef float  f32x4  __attribute__((ext_vector_type(4)));

#define L_SEQ  4096
#define NFLAT  8192   /* padded 2L-1 = 8191 */

// flat offset of level l:  OFF(l) = 8192 - (8192>>l)
__device__ __forceinline__ int off_l(int l) { return 8192 - (8192 >> l); }

// ---- async global->LDS, 16B per lane; lds base must be wave-uniform --------
__device__ __forceinline__ void glds16(const bf16* g, bf16* l) {
  __builtin_amdgcn_global_load_lds(
      (const __attribute__((address_space(1))) unsigned int*)g,
      (__attribute__((address_space(3))) unsigned int*)l, 16, 0, 0);
}

// ---------------------------------------------------------------------------
// fp32 -> bf16 conversion, fused launches
// ---------------------------------------------------------------------------
__global__ __launch_bounds__(256) void cvt3_kernel(
    const float* __restrict__ a, const float* __restrict__ b, const float* __restrict__ c,
    bf16* __restrict__ x, bf16* __restrict__ y, bf16* __restrict__ z) {
  const int s = blockIdx.y;
  const float* src = (s == 0) ? a : (s == 1) ? b : c;
  bf16*        dst = (s == 0) ? x : (s == 1) ? y : z;
  const int i = blockIdx.x * 256 + threadIdx.x;   // < 2097152 by grid
  const float4 v = ((const float4*)src)[i];
  bf16x4 o;
  o[0] = (bf16)v.x; o[1] = (bf16)v.y; o[2] = (bf16)v.z; o[3] = (bf16)v.w;
  *(bf16x4*)(dst + (size_t)i * 4) = o;
}

__global__ __launch_bounds__(256) void cvt4_kernel(
    const float* __restrict__ a, const float* __restrict__ b,
    const float* __restrict__ c, const float* __restrict__ d,
    bf16* __restrict__ x, bf16* __restrict__ y, bf16* __restrict__ z, bf16* __restrict__ w) {
  const int s = blockIdx.y;
  const float* src = (s == 0) ? a : (s == 1) ? b : (s == 2) ? c : d;
  bf16*        dst = (s == 0) ? x : (s == 1) ? y : (s == 2) ? z : w;
  const int i = blockIdx.x * 256 + threadIdx.x;   // < 262144 by grid
  const float4 v = ((const float4*)src)[i];
  bf16x4 o;
  o[0] = (bf16)v.x; o[1] = (bf16)v.y; o[2] = (bf16)v.z; o[3] = (bf16)v.w;
  *(bf16x4*)(dst + (size_t)i * 4) = o;
}

// ---------------------------------------------------------------------------
// GEMM core: C(128x128) = A(128xK) * W(128xK)^T, K=1024, bf16, m97 structure.
// ---------------------------------------------------------------------------
__device__ __forceinline__ void gemm_core(const bf16* __restrict__ A,
                                          const bf16* __restrict__ W,
                                          int tm, int tn, bf16* As, bf16* Bs,
                                          f32x4 (&acc)[4][4]) {
  const int tid  = threadIdx.x;
  const int wave = tid >> 6, lane = tid & 63;
  const int wm = (wave >> 1) * 64, wn = (wave & 1) * 64;
  for (int k0 = 0; k0 < 1024; k0 += 32) {
#pragma unroll
    for (int c = 0; c < 2; c++) {
      const int base = c * 4096 + wave * 1024;  // wave-uniform byte offset in 8KB tile
      const int off  = base + lane * 16;        // per-lane byte offset
      const int row  = off >> 6;                // 64B per 32-elem row
      const int kk   = (off & 63) >> 1;         // bf16 col within row
      glds16(A + (size_t)(tm * 128 + row) * 1024 + k0 + kk, As + (base >> 1));
      glds16(W + (size_t)(tn * 128 + row) * 1024 + k0 + kk, Bs + (base >> 1));
    }
    __syncthreads();
    bf16x8 af[4], bfr[4];
#pragma unroll
    for (int i = 0; i < 4; i++) {
      af[i]  = *(const bf16x8*)&As[(wm + i * 16 + (lane & 15)) * 32 + (lane >> 4) * 8];
      bfr[i] = *(const bf16x8*)&Bs[(wn + i * 16 + (lane & 15)) * 32 + (lane >> 4) * 8];
    }
#pragma unroll
    for (int i = 0; i < 4; i++)
#pragma unroll
      for (int j = 0; j < 4; j++)
        acc[i][j] = __builtin_amdgcn_mfma_f32_16x16x32_bf16(af[i], bfr[j], acc[i][j], 0, 0, 0);
    __syncthreads();
  }
}

// QKV projections. grid = (512, 3). Writes Q -> [bh][l][64], K/V -> flat level-0.
__global__ __launch_bounds__(256) void gemm_qkv_kernel(
    const bf16* __restrict__ qx, const bf16* __restrict__ kx, const bf16* __restrict__ vx,
    const bf16* __restrict__ wq, const bf16* __restrict__ wk, const bf16* __restrict__ wv,
    bf16* __restrict__ Qb, bf16* __restrict__ fK, bf16* __restrict__ fV) {
  __shared__ __align__(16) bf16 As[128 * 32];
  __shared__ __align__(16) bf16 Bs[128 * 32];
  const int z = blockIdx.y;
  const bf16* A = (z == 0) ? qx : (z == 1) ? kx : vx;
  const bf16* W = (z == 0) ? wq : (z == 1) ? wk : wv;
  bf16* D       = (z == 0) ? Qb : (z == 1) ? fK : fV;
  const int lstr = (z == 0) ? L_SEQ : NFLAT;
  const int tm = blockIdx.x & 63, tn = blockIdx.x >> 6;
  f32x4 acc[4][4] = {};
  gemm_core(A, W, tm, tn, As, Bs, acc);
  const int lane = threadIdx.x & 63, wave = threadIdx.x >> 6;
  const int m0 = tm * 128 + (wave >> 1) * 64 + (lane >> 4) * 4;
  const int n0 = tn * 128 + (wave & 1) * 64 + (lane & 15);
#pragma unroll
  for (int i = 0; i < 4; i++)
#pragma unroll
    for (int j = 0; j < 4; j++)
#pragma unroll
      for (int r = 0; r < 4; r++) {
        const int m = m0 + i * 16 + r;
        const int n = n0 + j * 16;
        const int b = m >> 12, l = m & 4095;
        const int h = n >> 6,  dh = n & 63;
        D[((size_t)(b * 16 + h) * lstr + l) * 64 + dh] = (bf16)acc[i][j][r];
      }
}

// Output projection + bias, f32 out (8192 x 1024). grid = 512.
__global__ __launch_bounds__(256) void gemm_out_kernel(
    const bf16* __restrict__ Ob, const bf16* __restrict__ wo,
    const float* __restrict__ bo, float* __restrict__ out) {
  __shared__ __align__(16) bf16 As[128 * 32];
  __shared__ __align__(16) bf16 Bs[128 * 32];
  const int tm = blockIdx.x & 63, tn = blockIdx.x >> 6;
  f32x4 acc[4][4] = {};
  gemm_core(Ob, wo, tm, tn, As, Bs, acc);
  const int lane = threadIdx.x & 63, wave = threadIdx.x >> 6;
  const int m0 = tm * 128 + (wave >> 1) * 64 + (lane >> 4) * 4;
  const int n0 = tn * 128 + (wave & 1) * 64 + (lane & 15);
#pragma unroll
  for (int i = 0; i < 4; i++)
#pragma unroll
    for (int j = 0; j < 4; j++)
#pragma unroll
      for (int r = 0; r < 4; r++) {
        const int m = m0 + i * 16 + r;
        const int n = n0 + j * 16;
        out[(size_t)m * 1024 + n] = acc[i][j][r] + bo[n];
      }
}

// ---------------------------------------------------------------------------
// Tree levels 1..6: block = 1 wave, owns (bh, 64-leaf group). Leaves staged in
// LDS via global_load_lds (breaks the global-alias serialization of the loads:
// stores go to global, loads come from LDS -> independent, pipelined).
// Lane = column d. Binary-counter accumulation in f32 registers.
// grid = (64, 32)
// ---------------------------------------------------------------------------
__global__ __launch_bounds__(64) void tree_l16(bf16* __restrict__ fK, bf16* __restrict__ fV) {
  __shared__ __align__(16) bf16 Kl[64 * 64];
  __shared__ __align__(16) bf16 Vl[64 * 64];
  const int g = blockIdx.x, bh = blockIdx.y;
  const int lane = threadIdx.x;
  const size_t fb = (size_t)bh * NFLAT * 64;
  const size_t leafbase = fb + (size_t)g * 64 * 64;
#pragma unroll
  for (int it = 0; it < 8; it++) {
    glds16(fK + leafbase + it * 512 + lane * 8, Kl + it * 512);
    glds16(fV + leafbase + it * 512 + lane * 8, Vl + it * 512);
  }
  asm volatile("s_waitcnt vmcnt(0)" ::: "memory");
  __syncthreads();

  float pk[7], pv[7];
#pragma unroll
  for (int i = 0; i < 64; i++) {
    float ck = (float)Kl[i * 64 + lane];
    float cv = (float)Vl[i * 64 + lane];
#pragma unroll
    for (int l = 1; l <= 6; l++) {
      if (((i + 1) & ((1 << l) - 1)) != 0) { pk[l] = ck; pv[l] = cv; break; }
      ck += pk[l]; cv += pv[l];
      const int j = (g * 64 + i) >> l;
      fK[fb + (size_t)(off_l(l) + j) * 64 + lane] = (bf16)(ck * (1.0f / (1 << l)));
      fV[fb + (size_t)(off_l(l) + j) * 64 + lane] = (bf16)cv;
    }
  }
}

// ---------------------------------------------------------------------------
// Tree levels 7..12 from level 6 (64 rows per bh). Block = 1 wave per bh,
// lane = column d: zero cross-lane traffic, f32 LDS ping down the levels.
// grid = 32
// ---------------------------------------------------------------------------
__global__ __launch_bounds__(64) void tree_l712(bf16* __restrict__ fK, bf16* __restrict__ fV) {
  __shared__ float Ks[64 * 64];
  __shared__ float Vs[64 * 64];
  const int bh = blockIdx.x, d = threadIdx.x;
  const size_t fb = (size_t)bh * NFLAT * 64;
#pragma unroll 8
  for (int i = 0; i < 64; i++) {
    Ks[i * 64 + d] = (float)fK[fb + (size_t)(8064 + i) * 64 + d];  // off_l(6)=8064
    Vs[i * 64 + d] = (float)fV[fb + (size_t)(8064 + i) * 64 + d];
  }
  // single wave: per-lane column ownership, no cross-lane hazards
#pragma unroll
  for (int l = 7; l <= 12; l++) {
    const int cnt = 4096 >> l;   // 32,16,8,4,2,1
    for (int j = 0; j < cnt; j++) {
      const float k = (Ks[(2 * j) * 64 + d] + Ks[(2 * j + 1) * 64 + d]) * 0.5f;
      const float v =  Vs[(2 * j) * 64 + d] + Vs[(2 * j + 1) * 64 + d];
      Ks[j * 64 + d] = k;
      Vs[j * 64 + d] = v;
      fK[fb + (size_t)(off_l(l) + j) * 64 + d] = (bf16)k;
      fV[fb + (size_t)(off_l(l) + j) * 64 + d] = (bf16)v;
    }
  }
}

// ---------------------------------------------------------------------------
// Sparse attention: per token 13 candidates (self + levels 0..11).
//   neighbor flat idx at level l = OFF(l) + ((n>>l)^1); valid iff (n>>l)&1.
// Block = 1 wave = 64 consecutive tokens of one (b,h); 132 K/V rows in LDS
// (XOR-swizzled chunks). grid = (64, 32)
// ---------------------------------------------------------------------------
__global__ __launch_bounds__(64) void attn_kernel(
    const bf16* __restrict__ Qb, const bf16* __restrict__ fK,
    const bf16* __restrict__ fV, bf16* __restrict__ Ob) {
  __shared__ __align__(16) unsigned short Kl[132 * 64];
  __shared__ __align__(16) unsigned short Vl[132 * 64];
  const int t0  = blockIdx.x * 64;
  const int bh  = blockIdx.y;
  const int tid = threadIdx.x;
  const size_t fb = (size_t)bh * NFLAT * 64;

  for (int u = tid; u < 132 * 8; u += 64) {
    const int r = u >> 3, c = u & 7;
    int flat;
    if      (r < 64)  flat = t0 + r;
    else if (r < 96)  flat = 4096 + (t0 >> 1) + (r - 64);
    else if (r < 112) flat = 6144 + (t0 >> 2) + (r - 96);
    else if (r < 120) flat = 7168 + (t0 >> 3) + (r - 112);
    else if (r < 124) flat = 7680 + (t0 >> 4) + (r - 120);
    else if (r < 126) flat = 7936 + (t0 >> 5) + (r - 124);
    else { const int l = r - 120; flat = (8192 - (8192 >> l) + (t0 >> l)) ^ 1; }
    const int cc = c ^ (r & 7);
    const uint4 kk = *(const uint4*)((const char*)(fK + fb + (size_t)flat * 64) + c * 16);
    const uint4 vv = *(const uint4*)((const char*)(fV + fb + (size_t)flat * 64) + c * 16);
    *(uint4*)((char*)Kl + r * 128 + cc * 16) = kk;
    *(uint4*)((char*)Vl + r * 128 + cc * 16) = vv;
  }
  __syncthreads();

  const int n = t0 + tid;
  int rows[13];
  rows[0] = tid;
#pragma unroll
  for (int l = 0; l < 12; l++) {
    int r;
    if (l == 0)      r = tid ^ 1;
    else if (l <= 5) r = (128 - (128 >> l)) + (((n >> l) ^ 1) - (t0 >> l));
    else             r = 126 + (l - 6);
    rows[l + 1] = r;
  }

  float q[64];
  const bf16* Qr = Qb + ((size_t)bh * L_SEQ + n) * 64;
#pragma unroll
  for (int c = 0; c < 8; c++) {
    bf16x8 v = *(const bf16x8*)(Qr + c * 8);
#pragma unroll
    for (int j = 0; j < 8; j++) q[c * 8 + j] = (float)v[j];
  }

  float lg[13];
#pragma unroll
  for (int v = 0; v < 13; v++) {
    const int r = rows[v];
    float a = 0.f;
#pragma unroll
    for (int c = 0; c < 8; c++) {
      const int cc = c ^ (r & 7);
      const bf16x8 kv = *(const bf16x8*)((const char*)Kl + r * 128 + cc * 16);
#pragma unroll
      for (int j = 0; j < 8; j++) a += q[c * 8 + j] * (float)kv[j];
    }
    lg[v] = a * 0.125f;
  }
#pragma unroll
  for (int v = 1; v < 13; v++)
    if (!((n >> (v - 1)) & 1)) lg[v] = -1e30f;

  float mx = lg[0];
#pragma unroll
  for (int v = 1; v < 13; v++) mx = fmaxf(mx, lg[v]);
  float w[13], s = 0.f;
#pragma unroll
  for (int v = 0; v < 13; v++) { w[v] = __expf(lg[v] - mx); s += w[v]; }
  const float inv = 1.0f / s;

  float o[64];
#pragma unroll
  for (int d = 0; d < 64; d++) o[d] = 0.f;
#pragma unroll
  for (int v = 0; v < 13; v++) {
    const int r = rows[v];
    const float wv = w[v];
#pragma unroll
    for (int c = 0; c < 8; c++) {
      const int cc = c ^ (r & 7);
      const bf16x8 vv = *(const bf16x8*)((const char*)Vl + r * 128 + cc * 16);
#pragma unroll
      for (int j = 0; j < 8; j++) o[c * 8 + j] += wv * (float)vv[j];
    }
  }

  bf16* Or = Ob + ((size_t)(bh >> 4) * L_SEQ + n) * 1024 + (size_t)(bh & 15) * 64;
#pragma unroll
  for (int c = 0; c < 8; c++) {
    bf16x8 ov;
#pragma unroll
    for (int j = 0; j < 8; j++) ov[j] = (bf16)(o[c * 8 + j] * inv);
    *(bf16x8*)(Or + c * 8) = ov;
  }
}

// ---------------------------------------------------------------------------
extern "C" void kernel_launch(void* const* d_in, const int* in_sizes, int n_in,
                              void* d_out, int out_size, void* d_ws, size_t ws_size,
                              hipStream_t stream) {
  const float* query = (const float*)d_in[0];
  const float* key   = (const float*)d_in[1];
  const float* value = (const float*)d_in[2];
  const float* Wq    = (const float*)d_in[3];
  const float* Wk    = (const float*)d_in[4];
  const float* Wv    = (const float*)d_in[5];
  const float* Wo    = (const float*)d_in[6];
  const float* bo    = (const float*)d_in[7];
  float* out = (float*)d_out;

  char* ws = (char*)d_ws;
  size_t off = 0;
  auto take = [&](size_t bytes) -> void* {
    void* p = ws + off;
    off += (bytes + 255) & ~(size_t)255;
    return p;
  };
  const size_t XB = (size_t)8192 * 1024 * 2;   // 16.78 MB
  const size_t WB = (size_t)1024 * 1024 * 2;   //  2.10 MB
  bf16* qx  = (bf16*)take(XB);
  bf16* kx  = (bf16*)take(XB);
  bf16* vx  = (bf16*)take(XB);
  bf16* wqx = (bf16*)take(WB);
  bf16* wkx = (bf16*)take(WB);
  bf16* wvx = (bf16*)take(WB);
  bf16* wox = (bf16*)take(WB);
  bf16* Qb  = (bf16*)take((size_t)32 * L_SEQ * 64 * 2);   // 16.78 MB
  bf16* fK  = (bf16*)take((size_t)32 * NFLAT * 64 * 2);   // 33.55 MB
  bf16* fV  = (bf16*)take((size_t)32 * NFLAT * 64 * 2);   // 33.55 MB
  bf16* Ob  = qx;  // alias: qx's last read is gemm_qkv; Ob first written by attn
  (void)in_sizes; (void)n_in; (void)out_size; (void)ws_size;

  // 1. fp32 -> bf16 (2 launches)
  cvt3_kernel<<<dim3(8192, 3), 256, 0, stream>>>(query, key, value, qx, kx, vx);
  cvt4_kernel<<<dim3(1024, 4), 256, 0, stream>>>(Wq, Wk, Wv, Wo, wqx, wkx, wvx, wox);

  // 2. Q/K/V projections
  gemm_qkv_kernel<<<dim3(512, 3), 256, 0, stream>>>(qx, kx, vx, wqx, wkx, wvx, Qb, fK, fV);

  // 3. hierarchy
  tree_l16 <<<dim3(64, 32), 64, 0, stream>>>(fK, fV);
  tree_l712<<<32, 64, 0, stream>>>(fK, fV);

  // 4. sparse attention
  attn_kernel<<<dim3(64, 32), 64, 0, stream>>>(Qb, fK, fV, Ob);

  // 5. output projection
  gemm_out_kernel<<<512, 256, 0, stream>>>(Ob, wox, bo, out);
}